// Round 13
// baseline (82.503 us; speedup 1.0000x reference)
//
#include <hip/hip_runtime.h>
#include <hip/hip_bf16.h>
#include <stdint.h>

#define Bn 2
#define Np 50000
#define Cc 81
#define CM1 80
#define KSEL 2048
#define NDET 100
#define NBUCK 2048
#define BUCK_BASE 0x3D000000u
#define BUCK_SHIFT 15
#define SELCAP 4096
#define IMG_W 1333.0f
#define IMG_H 800.0f
#define SCORE_TH 0.05f
#define MIN_SZ 0.01f
#define NMS_TH 0.5f
#define LBLOFF 1401.0f
#define BBOX_CLIP_F 4.135166556742356f
#define CHUNK 32       // proposals per wave (2 rounds of 16)
#define QCAP 320       // >= 16 proposals * 19 max emits per round
#define BLKX 391       // ceil(Np / (4*CHUNK))
#define WPI  (BLKX*4)  // wave segments per image
#define RS_WPB 4       // runsort waves per block
#define WIN 256        // tail pipeline window

typedef unsigned long long u64;
typedef unsigned int u32;

__device__ __forceinline__ u64 shfl64(u64 v, int src) {
  int lo = __shfl((int)(u32)v, src, 64);
  int hi = __shfl((int)(u32)(v >> 32), src, 64);
  return ((u64)(u32)hi << 32) | (u32)lo;
}

// Torchvision BoxCoder.decode + clip, non-contracted fp32 to match reference.
__device__ __forceinline__ void decode_box(int row, int c,
    const float* __restrict__ reg, const float* __restrict__ props,
    float& x1, float& y1, float& x2, float& y2) {
  const float4 pr = *reinterpret_cast<const float4*>(props + (size_t)row * 4);
  float w = __fsub_rn(pr.z, pr.x), h = __fsub_rn(pr.w, pr.y);
  float cx = __fadd_rn(pr.x, 0.5f * w), cy = __fadd_rn(pr.y, 0.5f * h);
  const float4 rel = *reinterpret_cast<const float4*>(reg + ((size_t)row * Cc + c) * 4);
  float dx = __fdiv_rn(rel.x, 10.f), dy = __fdiv_rn(rel.y, 10.f);
  float dw = fminf(__fdiv_rn(rel.z, 5.f), BBOX_CLIP_F);
  float dh = fminf(__fdiv_rn(rel.w, 5.f), BBOX_CLIP_F);
  float pcx = __fadd_rn(__fmul_rn(dx, w), cx);
  float pcy = __fadd_rn(__fmul_rn(dy, h), cy);
  float pw = __fmul_rn(expf(dw), w);
  float ph = __fmul_rn(expf(dh), h);
  x1 = fminf(fmaxf(__fsub_rn(pcx, 0.5f * pw), 0.f), IMG_W);
  y1 = fminf(fmaxf(__fsub_rn(pcy, 0.5f * ph), 0.f), IMG_H);
  x2 = fminf(fmaxf(__fadd_rn(pcx, 0.5f * pw), 0.f), IMG_W);
  y2 = fminf(fmaxf(__fadd_rn(pcy, 0.5f * ph), 0.f), IMG_H);
}

// Batched drain (r9-proven): 64 lanes decode+minsize-filter queued keys,
// compact survivors to the private segment, count into the LDS histogram.
__device__ __forceinline__ u32 drain(const u64* Qb, u32 n, int lane, int b,
    const float* __restrict__ reg, const float* __restrict__ props,
    u32* hist, u64* seg, u32 wout) {
  for (u32 qb = 0; qb < n; qb += 64) {
    const bool act = (qb + (u32)lane) < n;
    u64 key = act ? Qb[qb + lane] : 0ull;
    bool valid = false;
    u32 sb = 0;
    if (act) {
      sb = (u32)(key >> 32);
      const u32 idx = ~(u32)key;
      const int pn = (int)(idx / CM1);
      const int c = (int)(idx - (u32)pn * CM1) + 1;
      float x1, y1, x2, y2;
      decode_box(b * Np + pn, c, reg, props, x1, y1, x2, y2);
      valid = (__fsub_rn(x2, x1) >= MIN_SZ) && (__fsub_rn(y2, y1) >= MIN_SZ);
    }
    const u64 bal = __ballot(valid);
    if (valid) {
      seg[wout + (u32)__popcll(bal & ((1ull << lane) - 1ull))] = key;
      u32 bk = (sb - BUCK_BASE) >> BUCK_SHIFT;
      if (bk > (u32)(NBUCK - 1)) bk = NBUCK - 1;
      atomicAdd(&hist[bk], 1u);
    }
    wout += (u32)__popcll(bal);
  }
  return wout;
}

// Pass A (r12-proven): direct-register logits loads, 2 rounds of 16
// proposals per wave, prefix-scan emit, drain per round.
__global__ __launch_bounds__(256, 4) void passA_kernel(
    const float* __restrict__ logits, const float* __restrict__ reg,
    const float* __restrict__ props, u64* __restrict__ wseg,
    u32* __restrict__ wcnt, u32* __restrict__ ghist)
{
  __shared__ u64 qbuf[4][QCAP];                        // 10240 B
  __shared__ u32 hist[NBUCK];                          // 8192 B
  const int b = blockIdx.y;
  const int tid = threadIdx.x;
  const int wave = tid >> 6, lane = tid & 63;
  for (int i = tid; i < NBUCK; i += 256) hist[i] = 0;
  __syncthreads();

  const int wslot = (blockIdx.x << 2) + wave;
  u64* Q = qbuf[wave];
  u64* seg = wseg + (size_t)(b * WPI + wslot) * QCAP;
  u32 wout = 0;
  const int p = lane >> 2, qd = lane & 3;
  const int cnt_k = (qd == 3) ? 18 : 21;
  #pragma unroll
  for (int r = 0; r < 2; ++r) {
    const int n0 = wslot * CHUNK + r * 16;
    if (n0 >= Np) break;
    const int n_ = n0 + p;
    const float* lrow = logits + ((size_t)b * Np + n_) * Cc + qd * 21;
    float ev[21];
    #pragma unroll
    for (int k = 0; k < 21; ++k)
      ev[k] = (k < cnt_k) ? lrow[k] : -3.4e38f;
    float m = ev[0];
    #pragma unroll
    for (int k = 1; k < 21; ++k) m = fmaxf(m, ev[k]);
    m = fmaxf(m, __shfl_xor(m, 1, 64));
    m = fmaxf(m, __shfl_xor(m, 2, 64));
    float s = 0.f;
    #pragma unroll
    for (int k = 0; k < 21; ++k) {
      ev[k] = (k < cnt_k) ? expf(ev[k] - m) : 0.f;
      s += ev[k];
    }
    s += __shfl_xor(s, 1, 64);
    s += __shfl_xor(s, 2, 64);
    const float thr = SCORE_TH * s;
    u32 emask = 0;
    #pragma unroll
    for (int k = 0; k < 21; ++k) {
      const int c = qd * 21 + k;
      if (c > 0 && ev[k] > thr) emask |= (1u << k);
    }
    const u32 mycnt = __popc(emask);
    u32 inc = mycnt;
    #pragma unroll
    for (int o = 1; o < 64; o <<= 1) {
      const u32 v = (u32)__shfl_up((int)inc, o, 64);
      if (lane >= o) inc += v;
    }
    u32 pos = inc - mycnt;
    const u32 qtot = (u32)__shfl((int)inc, 63, 64);
    u32 em = emask;
    while (em) {
      const int k = (int)__builtin_ctz(em);
      em &= em - 1;
      const int c = qd * 21 + k;
      const u32 sb = __float_as_uint(__fdiv_rn(ev[k], s));
      const u32 idx = (u32)(n_ * CM1 + (c - 1));
      Q[pos++] = ((u64)sb << 32) | (u32)(~idx);
    }
    wout = drain(Q, qtot, lane, b, reg, props, hist, seg, wout);
  }
  if (lane == 0) wcnt[b * WPI + wslot] = wout;
  __syncthreads();
  for (int i = tid; i < NBUCK; i += 256) {
    const u32 v = hist[i];
    if (v) atomicAdd(&ghist[b * NBUCK + i], v);   // fire-and-forget
  }
}

// Per image: T, exclusive suffix offsets, total; also zeroes bfill.
__global__ void thresh_kernel(const u32* __restrict__ ghist, u32* __restrict__ gT,
                              u32* __restrict__ gTot, u32* __restrict__ boffs,
                              u32* __restrict__ bfill) {
  const int b = blockIdx.x;
  const int lane = threadIdx.x;  // 64 threads
  const u32* h = ghist + b * NBUCK;
  u32* bo = boffs + b * NBUCK;
  const int SEG = NBUCK / 64;
  u32 segsum = 0;
  for (int t = 0; t < SEG; ++t) segsum += h[lane * SEG + t];
  u32 suf = segsum;
  #pragma unroll
  for (int o = 1; o < 64; o <<= 1) {
    const u32 v = (u32)__shfl_down((int)suf, o, 64);
    if (lane + o < 64) suf += v;
  }
  u32 acc = suf - segsum;
  int myT = -1; u32 totv = 0;
  for (int t = SEG - 1; t >= 0; --t) {
    const int bk = lane * SEG + t;
    bo[bk] = acc;
    bfill[b * NBUCK + bk] = 0u;
    acc += h[bk];
    if (myT < 0 && acc >= (u32)KSEL) { myT = bk; totv = acc; }
  }
  int Tg = myT;
  #pragma unroll
  for (int o = 32; o; o >>= 1) Tg = max(Tg, __shfl_xor(Tg, o, 64));
  if (Tg < 0) {
    if (lane == 0) { gT[b] = 0u; gTot[b] = (acc < (u32)SELCAP) ? acc : (u32)SELCAP; }
  } else if (myT == Tg) {
    gT[b] = (u32)Tg;
    gTot[b] = (totv < (u32)SELCAP) ? totv : (u32)SELCAP;
  }
}

// Scatter: wave-per-segment, per-bucket fill atomics.
__global__ __launch_bounds__(256) void scatter_kernel(
    const u64* __restrict__ wseg, const u32* __restrict__ wcnt,
    const u32* __restrict__ gT, const u32* __restrict__ boffs,
    u32* __restrict__ bfill, u64* __restrict__ skeys)
{
  const int b = blockIdx.y;
  const u32 T = gT[b];
  const int wave = threadIdx.x >> 6, lane = threadIdx.x & 63;
  const u32 sgi = blockIdx.x * 4 + wave;
  if (sgi >= (u32)WPI) return;
  const u32 cnt = wcnt[b * WPI + sgi];
  const u64* seg = wseg + (size_t)(b * WPI + sgi) * QCAP;
  for (u32 i = lane; i < cnt; i += 64) {
    const u64 key = seg[i];
    const u32 sb = (u32)(key >> 32);
    u32 bk = (sb - BUCK_BASE) >> BUCK_SHIFT;
    if (bk > (u32)(NBUCK - 1)) bk = NBUCK - 1;
    if (bk >= T) {
      const u32 pos = boffs[b * NBUCK + bk] + atomicAdd(&bfill[b * NBUCK + bk], 1u);
      if (pos < (u32)SELCAP) skeys[(size_t)b * SELCAP + pos] = key;
    }
  }
}

// Intra-bucket rank sort, wave-per-bucket across the grid (r6/r9-proven).
__global__ __launch_bounds__(256) void runsort_kernel(
    const u64* __restrict__ skeys, u64* __restrict__ skeys2,
    const u32* __restrict__ gT, const u32* __restrict__ gTot,
    const u32* __restrict__ boffs, const u32* __restrict__ bfill)
{
  const int b = blockIdx.y;
  const int wave = threadIdx.x >> 6, lane = threadIdx.x & 63;
  const u32 bk = blockIdx.x * RS_WPB + wave;
  if (bk >= (u32)NBUCK || bk < gT[b]) return;
  const u32 total = gTot[b];
  const u32 start = boffs[b * NBUCK + bk];
  u32 L = bfill[b * NBUCK + bk];
  if (L == 0 || start >= (u32)KSEL || start >= total) return;
  if (start + L > total) L = total - start;
  const u64* run = skeys + (size_t)b * SELCAP + start;
  u64* dst = skeys2 + (size_t)b * SELCAP + start;
  if (L <= 128u) {
    const u64 k0 = (lane < (int)L) ? run[lane] : 0ull;
    const u64 k1 = (64 + lane < (int)L) ? run[64 + lane] : 0ull;
    u32 r0 = 0, r1 = 0;
    #pragma unroll
    for (int l = 0; l < 64; ++l) {
      const u64 o0 = shfl64(k0, l);
      const u64 o1 = shfl64(k1, l);
      r0 += (o0 > k0) + (o1 > k0);
      r1 += (o0 > k1) + (o1 > k1);
    }
    if (lane < (int)L) dst[r0] = k0;
    if (64 + lane < (int)L) dst[r1] = k1;
  } else {
    for (u32 i = lane; i < L; i += 64) {
      const u64 k = run[i];
      u32 r = 0;
      for (u32 q = 0; q < L; ++q) r += (run[q] > k);
      dst[r] = k;
    }
  }
}

// Pipelined lazy tail: waves 1-3 decode window w+1 while wave 0 NMS-es
// window w (disjoint double-buffer between barriers). Only windows reached
// before 100 keeps are processed (~2-3 of 8). One block per image.
__global__ __launch_bounds__(256) void tail_kernel(
    const u64* __restrict__ skeys2, const u32* __restrict__ gTot,
    const float* __restrict__ reg, const float* __restrict__ props,
    float* __restrict__ out)
{
  __shared__ float bfx1[2][WIN], bfy1[2][WIN], bfx2[2][WIN], bfy2[2][WIN];
  __shared__ float bfsc[2][WIN], bflb[2][WIN];               // 12 KB
  __shared__ float kox1[NDET], koy1[NDET], kox2[NDET], koy2[NDET], kar[NDET];
  __shared__ float kx1[NDET], ky1[NDET], kx2[NDET], ky2[NDET], ksc[NDET], klb[NDET];
  __shared__ u32 sh_kc;
  const int b = blockIdx.x;
  const int tid = threadIdx.x;
  const int wave = tid >> 6, lane = tid & 63;
  const u32 totalg = gTot[b];
  const u32 total = (totalg < (u32)KSEL) ? totalg : (u32)KSEL;
  if (tid == 0) sh_kc = 0;

  // Decode window 0 with all 256 threads.
  {
    const u32 pos = (u32)tid;
    float x1 = 0, y1 = 0, x2 = 0, y2 = 0, sc = 0, lb = 0;
    if (pos < total) {
      const u64 key = skeys2[(size_t)b * SELCAP + pos];
      if (key) {
        const u32 sb = (u32)(key >> 32);
        const u32 idx = ~(u32)key;
        const int n_ = (int)(idx / CM1);
        const int c = (int)(idx % CM1) + 1;
        sc = __uint_as_float(sb);
        decode_box(b * Np + n_, c, reg, props, x1, y1, x2, y2);
        lb = (float)c;
      }
    }
    bfx1[0][tid] = x1; bfy1[0][tid] = y1; bfx2[0][tid] = x2; bfy2[0][tid] = y2;
    bfsc[0][tid] = sc; bflb[0][tid] = lb;
  }
  __syncthreads();

  const u32 nwin = (total + WIN - 1) / WIN;
  int kc = 0;
  for (u32 w = 0; w < nwin && kc < NDET; ++w) {
    const u32 cur = w & 1, nxt = cur ^ 1;
    if (wave > 0) {
      // Waves 1-3: decode window w+1 into the other buffer (192 threads).
      const u32 wb = (w + 1) * WIN;
      for (u32 e = (u32)(tid - 64); e < (u32)WIN; e += 192) {
        const u32 pos = wb + e;
        float x1 = 0, y1 = 0, x2 = 0, y2 = 0, sc = 0, lb = 0;
        if (pos < total) {
          const u64 key = skeys2[(size_t)b * SELCAP + pos];
          if (key) {
            const u32 sb = (u32)(key >> 32);
            const u32 idx = ~(u32)key;
            const int n_ = (int)(idx / CM1);
            const int c = (int)(idx % CM1) + 1;
            sc = __uint_as_float(sb);
            decode_box(b * Np + n_, c, reg, props, x1, y1, x2, y2);
            lb = (float)c;
          }
        }
        bfx1[nxt][e] = x1; bfy1[nxt][e] = y1; bfx2[nxt][e] = x2; bfy2[nxt][e] = y2;
        bfsc[nxt][e] = sc; bflb[nxt][e] = lb;
      }
    } else {
      // Wave 0: greedy NMS over window w (r10-proven loop, LDS source).
      int kcl = kc;
      const u32 wb = w * WIN;
      for (u32 base = 0; base < (u32)WIN && kcl < NDET; base += 64) {
        const u32 pos = wb + base + lane;
        const bool inb = pos < total;
        const u32 e = base + lane;
        const float x1 = bfx1[cur][e], y1 = bfy1[cur][e];
        const float x2 = bfx2[cur][e], y2 = bfy2[cur][e];
        const float sc = bfsc[cur][e], lb = bflb[cur][e];
        const float offv = __fmul_rn(lb, LBLOFF);
        const float ox1 = __fadd_rn(x1, offv), oy1 = __fadd_rn(y1, offv);
        const float ox2 = __fadd_rn(x2, offv), oy2 = __fadd_rn(y2, offv);
        const float ar = __fmul_rn(__fsub_rn(ox2, ox1), __fsub_rn(oy2, oy1));
        const bool valid = inb && (sc > 0.f);
        bool sup = false;
        for (int k = 0; k < kcl; ++k) {
          const float ltx = fmaxf(ox1, kox1[k]), lty = fmaxf(oy1, koy1[k]);
          const float rbx = fminf(ox2, kox2[k]), rby = fminf(oy2, koy2[k]);
          const float wx = fmaxf(__fsub_rn(rbx, ltx), 0.f);
          const float wy = fmaxf(__fsub_rn(rby, lty), 0.f);
          const float inter = __fmul_rn(wx, wy);
          const float denom = __fadd_rn(__fsub_rn(__fadd_rn(ar, kar[k]), inter), 1e-9f);
          if (__fdiv_rn(inter, denom) > NMS_TH) sup = true;
        }
        u64 rem = __ballot(sup) | ~__ballot(valid);
        u64 todo = ~rem;
        while (todo && kcl < NDET) {
          const int jb = (int)__builtin_ctzll(todo);
          const float bx1 = __shfl(ox1, jb, 64), by1 = __shfl(oy1, jb, 64);
          const float bx2 = __shfl(ox2, jb, 64), by2 = __shfl(oy2, jb, 64);
          const float ba  = __shfl(ar, jb, 64);
          if (lane == jb) {
            kox1[kcl] = ox1; koy1[kcl] = oy1; kox2[kcl] = ox2; koy2[kcl] = oy2; kar[kcl] = ar;
            kx1[kcl] = x1; ky1[kcl] = y1; kx2[kcl] = x2; ky2[kcl] = y2; ksc[kcl] = sc; klb[kcl] = lb;
          }
          const float ltx = fmaxf(ox1, bx1), lty = fmaxf(oy1, by1);
          const float rbx = fminf(ox2, bx2), rby = fminf(oy2, by2);
          const float wx = fmaxf(__fsub_rn(rbx, ltx), 0.f);
          const float wy = fmaxf(__fsub_rn(rby, lty), 0.f);
          const float inter = __fmul_rn(wx, wy);
          const float denom = __fadd_rn(__fsub_rn(__fadd_rn(ar, ba), inter), 1e-9f);
          const u64 wsup = __ballot(__fdiv_rn(inter, denom) > NMS_TH);
          rem |= wsup;
          todo &= ~rem;
          todo &= ~(1ull << jb);
          ++kcl;
        }
      }
      if (lane == 0) sh_kc = (u32)kcl;
    }
    __syncthreads();
    kc = (int)sh_kc;
  }

  // Output: first min(kc,100) kept, padded with zeros / label -1.
  const int kcl = (kc < NDET) ? kc : NDET;
  for (int k = tid; k < NDET; k += 256) {
    float bx1 = 0, by1 = 0, bx2 = 0, by2 = 0, sc = 0, lb = -1.f;
    if (k < kcl) {
      bx1 = kx1[k]; by1 = ky1[k]; bx2 = kx2[k]; by2 = ky2[k];
      sc = ksc[k]; lb = klb[k];
    }
    float* ob = out + (size_t)b * NDET * 4;
    ob[k * 4 + 0] = bx1; ob[k * 4 + 1] = by1;
    ob[k * 4 + 2] = bx2; ob[k * 4 + 3] = by2;
    out[Bn * NDET * 4 + b * NDET + k] = sc;
    out[Bn * NDET * 4 + Bn * NDET + b * NDET + k] = lb;
  }
}

extern "C" void kernel_launch(void* const* d_in, const int* in_sizes, int n_in,
                              void* d_out, int out_size, void* d_ws, size_t ws_size,
                              hipStream_t stream) {
  const float* logits = (const float*)d_in[0];
  const float* reg    = (const float*)d_in[1];
  const float* props  = (const float*)d_in[2];
  float* out = (float*)d_out;
  char* ws = (char*)d_ws;

  // Layout: [header | ghist]  <- memset 0 each call (16 KB)
  //         [bfill (zeroed by thresh) | boffs | skeys | skeys2 | wcnt | wseg]
  u32* gT   = (u32*)ws;                        // 2 u32
  u32* gTot = (u32*)(ws + 16);                 // 2 u32
  size_t off = 64;
  u32* ghist  = (u32*)(ws + off); off += (size_t)Bn * NBUCK * 4;   // 16 KB
  const size_t memset_bytes = off;
  u32* bfill  = (u32*)(ws + off); off += (size_t)Bn * NBUCK * 4;   // 16 KB
  u32* boffs  = (u32*)(ws + off); off += (size_t)Bn * NBUCK * 4;   // 16 KB
  u64* skeys  = (u64*)(ws + off); off += (size_t)Bn * SELCAP * 8;  // 64 KB
  u64* skeys2 = (u64*)(ws + off); off += (size_t)Bn * SELCAP * 8;  // 64 KB
  u32* wcnt   = (u32*)(ws + off); off += (size_t)Bn * WPI * 4;     // 13 KB
  off = (off + 255) & ~(size_t)255;
  u64* wseg   = (u64*)(ws + off); off += (size_t)Bn * WPI * QCAP * 8;  // 8 MB
  (void)ws_size;

  hipMemsetAsync(d_ws, 0, memset_bytes, stream);
  passA_kernel<<<dim3(BLKX, Bn), 256, 0, stream>>>(logits, reg, props, wseg, wcnt, ghist);
  thresh_kernel<<<dim3(Bn), 64, 0, stream>>>(ghist, gT, gTot, boffs, bfill);
  scatter_kernel<<<dim3((WPI + 3) / 4, Bn), 256, 0, stream>>>(wseg, wcnt, gT, boffs, bfill, skeys);
  runsort_kernel<<<dim3(NBUCK / RS_WPB, Bn), 256, 0, stream>>>(skeys, skeys2, gT, gTot, boffs, bfill);
  tail_kernel<<<dim3(Bn), 256, 0, stream>>>(skeys2, gTot, reg, props, out);
}